// Round 1
// baseline (1060.564 us; speedup 1.0000x reference)
//
#include <hip/hip_runtime.h>
#include <math.h>

// Problem constants (B,H,L,D) = (8,8,2048,512)
#define FFT_N   512
#define HL      16384   // H*L = 8*2048

// One block (256 threads) per row. Radix-2 DIT FFT in LDS.
// Forward FFT -> gate by complex weight -> conj -> forward FFT -> Re()/N  (== IFFT real part)
__global__ __launch_bounds__(256) void sgn_fft_kernel(
    const float* __restrict__ x,
    const float* __restrict__ cw,   // (H,L,D,2) interleaved re,im
    float* __restrict__ out)
{
    __shared__ float2 s[FFT_N];
    __shared__ float2 t[FFT_N];
    __shared__ float2 tw[FFT_N / 2];   // tw[j] = exp(-2*pi*i*j/N)

    const int tid = threadIdx.x;
    const int row = blockIdx.x;
    const long long base  = (long long)row * FFT_N;
    const int hl          = row & (HL - 1);
    const long long wbase = (long long)hl * FFT_N * 2;

    // Twiddle table: 256 entries, one per thread. Accurate sincosf.
    {
        float ang = -(float)(2.0 * M_PI) * (float)tid / (float)FFT_N;
        float sv, cv;
        sincosf(ang, &sv, &cv);
        tw[tid] = make_float2(cv, sv);
    }

    // Load row, bit-reversed into s (real input, imag = 0)
    for (int i = tid; i < FFT_N; i += 256) {
        int r = __brev(i) >> 23;   // 9-bit reversal
        s[r] = make_float2(x[base + i], 0.0f);
    }
    __syncthreads();

    // ---- forward FFT on s (DIT, bit-reversed input -> natural output) ----
    #pragma unroll
    for (int m = 1; m <= 9; ++m) {
        const int half = 1 << (m - 1);
        const int j    = tid;                 // butterfly index 0..255
        const int pos  = j & (half - 1);
        const int grp  = j >> (m - 1);
        const int i0   = (grp << m) + pos;
        const int i1   = i0 + half;
        const float2 u = s[i0];
        const float2 v = s[i1];
        const float2 w = tw[pos << (9 - m)];
        const float vr = v.x * w.x - v.y * w.y;
        const float vi = v.x * w.y + v.y * w.x;
        s[i0] = make_float2(u.x + vr, u.y + vi);
        s[i1] = make_float2(u.x - vr, u.y - vi);
        __syncthreads();
    }

    // ---- gate: y = W * X ; store conj(y) bit-reversed into t ----
    for (int k = tid; k < FFT_N; k += 256) {
        const float2 X = s[k];
        const float wr = cw[wbase + 2 * k];
        const float wi = cw[wbase + 2 * k + 1];
        const float yr = wr * X.x - wi * X.y;
        const float yi = wr * X.y + wi * X.x;
        const int r = __brev(k) >> 23;
        t[r] = make_float2(yr, -yi);
    }
    __syncthreads();

    // ---- forward FFT on t ----
    #pragma unroll
    for (int m = 1; m <= 9; ++m) {
        const int half = 1 << (m - 1);
        const int j    = tid;
        const int pos  = j & (half - 1);
        const int grp  = j >> (m - 1);
        const int i0   = (grp << m) + pos;
        const int i1   = i0 + half;
        const float2 u = t[i0];
        const float2 v = t[i1];
        const float2 w = tw[pos << (9 - m)];
        const float vr = v.x * w.x - v.y * w.y;
        const float vi = v.x * w.y + v.y * w.x;
        t[i0] = make_float2(u.x + vr, u.y + vi);
        t[i1] = make_float2(u.x - vr, u.y - vi);
        __syncthreads();
    }

    // ---- out = Re(fft(conj(y))) / N  == Re(ifft(y)) ----
    const float invn = 1.0f / (float)FFT_N;
    for (int k = tid; k < FFT_N; k += 256) {
        out[base + k] = t[k].x * invn;
    }
}

extern "C" void kernel_launch(void* const* d_in, const int* in_sizes, int n_in,
                              void* d_out, int out_size, void* d_ws, size_t ws_size,
                              hipStream_t stream) {
    const float* x  = (const float*)d_in[0];   // (B,H,L,D) fp32
    // d_in[1] = mask (unused by the reference layer)
    const float* cw = (const float*)d_in[2];   // (H,L,D,2) fp32
    float* out = (float*)d_out;

    const int rows = in_sizes[0] / FFT_N;      // B*H*L = 131072
    sgn_fft_kernel<<<dim3(rows), dim3(256), 0, stream>>>(x, cw, out);
}

// Round 2
// 496.205 us; speedup vs baseline: 2.1373x; 2.1373x over previous
//
#include <hip/hip_runtime.h>
#include <math.h>

// (B,H,L,D) = (8,8,2048,512).  rows = B*H*L = 131072, FFT length 512.
// Identity used:  Re(ifft(W . fft(x))) == ifft(Wp . fft(x)),  Wp[k] = (W[k]+conj(W[(N-k)%N]))/2
// (Wp is Hermitian, so the result is real for real x). The map is C-linear, so two real rows
// sharing a weight row pack as z = x1 + i*x2:  ifft(Wp.fft(z)) = out1 + i*out2 exactly.
// Inverse via forward FFT:  ifft(G) = conj(fft(conj(G)))/N.

#define HL 16384      // H*L
#define NWAVE 4       // packed pairs (waves) per block

__device__ __forceinline__ float2 cadd(float2 a, float2 b){ return make_float2(a.x+b.x, a.y+b.y); }
__device__ __forceinline__ float2 csub(float2 a, float2 b){ return make_float2(a.x-b.x, a.y-b.y); }
__device__ __forceinline__ float2 cmul(float2 a, float2 b){ return make_float2(a.x*b.x - a.y*b.y, a.x*b.y + a.y*b.x); }

// 8-point DFT, natural order in and out, forward sign (e^{-2pi i nk/8}).
__device__ __forceinline__ void fft8(float2 x[8]) {
    const float c = 0.70710678118654752f;
    float2 u0 = cadd(x[0], x[4]);
    float2 u1 = cadd(x[1], x[5]);
    float2 u2 = cadd(x[2], x[6]);
    float2 u3 = cadd(x[3], x[7]);
    float2 v0 = csub(x[0], x[4]);
    float2 t1 = csub(x[1], x[5]);
    float2 t2 = csub(x[2], x[6]);
    float2 t3 = csub(x[3], x[7]);
    float2 v1 = make_float2(c*(t1.x + t1.y), c*(t1.y - t1.x));   // * W8^1
    float2 v2 = make_float2(t2.y, -t2.x);                        // * W8^2 = -i
    float2 v3 = make_float2(c*(t3.y - t3.x), -c*(t3.x + t3.y));  // * W8^3
    // FFT4(u) -> y0 y2 y4 y6
    float2 p0 = cadd(u0, u2), p1 = cadd(u1, u3);
    float2 q0 = csub(u0, u2), q1t = csub(u1, u3);
    float2 q1 = make_float2(q1t.y, -q1t.x);                      // * -i
    x[0] = cadd(p0, p1);
    x[4] = csub(p0, p1);
    x[2] = cadd(q0, q1);
    x[6] = csub(q0, q1);
    // FFT4(v) -> y1 y3 y5 y7
    float2 r0 = cadd(v0, v2), r1 = cadd(v1, v3);
    float2 s0 = csub(v0, v2), s1t = csub(v1, v3);
    float2 s1 = make_float2(s1t.y, -s1t.x);
    x[1] = cadd(r0, r1);
    x[5] = csub(r0, r1);
    x[3] = cadd(s0, s1);
    x[7] = csub(s0, s1);
}

// 512-pt forward FFT, one wave (64 lanes), 8 complex per lane.
// Input: lane with role r holds z[64*j + r] in v[j].
// Output: lane `lane` holds Z[ds(lane) + 64*j] in v[j], ds(r) = ((r&7)<<3)|(r>>3).
// LDS scratch: sre/sim = 8*72 floats each (per wave). 4 __syncthreads per call.
// All LDS access patterns are at worst 2-way bank-aliased (free on CDNA4).
__device__ __forceinline__ void fft512(float2 v[8], int role, int lane,
                                       float* sre, float* sim)
{
    const float TWOPI = 6.2831853071795864769f;
    // ---- stage 1: radix-8 over n1 (stride 64), twiddle W512^{role*k1} ----
    fft8(v);
    {
        float a = -TWOPI * (float)role * (1.0f/512.0f);
        float sn, cs; sincosf(a, &sn, &cs);
        const float2 w1 = make_float2(cs, sn);
        float2 w = w1;
        v[1] = cmul(v[1], w);
        #pragma unroll
        for (int k = 2; k < 8; ++k) { w = cmul(w, w1); v[k] = cmul(v[k], w); }
    }
    __syncthreads();                 // previous contents of scratch fully consumed
    #pragma unroll
    for (int k1 = 0; k1 < 8; ++k1) {
        sre[k1*72 + role] = v[k1].x;
        sim[k1*72 + role] = v[k1].y;
    }
    __syncthreads();
    // ---- stage 2: 8 independent 64-pt FFTs; radix-8 over m1 (stride 8) ----
    const int k1 = lane >> 3, m2 = lane & 7;
    float2 u[8];
    #pragma unroll
    for (int m1 = 0; m1 < 8; ++m1) {
        int a = k1*72 + 8*m1 + m2;
        u[m1] = make_float2(sre[a], sim[a]);
    }
    fft8(u);
    {
        float a = -TWOPI * (float)m2 * (1.0f/64.0f);
        float sn, cs; sincosf(a, &sn, &cs);
        const float2 w1 = make_float2(cs, sn);
        float2 w = w1;
        u[1] = cmul(u[1], w);
        #pragma unroll
        for (int j = 2; j < 8; ++j) { w = cmul(w, w1); u[j] = cmul(u[j], w); }
    }
    __syncthreads();                 // stage-2 reads done before overwrite
    #pragma unroll
    for (int j1 = 0; j1 < 8; ++j1) {
        int a = k1*72 + 9*j1 + m2;
        sre[a] = u[j1].x;
        sim[a] = u[j1].y;
    }
    __syncthreads();
    // ---- stage 3: radix-8 over m2 (stride 1), no twiddle ----
    const int j1 = lane & 7;         // stage-3 role = (k1, j1)
    float2 w8[8];
    #pragma unroll
    for (int m = 0; m < 8; ++m) {
        int a = k1*72 + 9*j1 + m;
        w8[m] = make_float2(sre[a], sim[a]);
    }
    fft8(w8);
    #pragma unroll
    for (int j = 0; j < 8; ++j) v[j] = w8[j];   // v[j2] = X[k1 + 8*j1 + 64*j2]
}

__global__ __launch_bounds__(256) void sgn_fft_r8(
    const float* __restrict__ x,
    const float* __restrict__ cw,    // (H,L,512,2)
    float* __restrict__ out)
{
    __shared__ float s_re[NWAVE][8*72];
    __shared__ float s_im[NWAVE][8*72];

    const int tid  = threadIdx.x;
    const int wid  = tid >> 6;       // wave id = batch-pair index b4 in [0,4)
    const int lane = tid & 63;
    const int hl   = blockIdx.x;     // weight row, shared by all 4 waves

    const int row1 = (wid       * HL + hl) * 512;   // batch b4
    const int row2 = ((wid + 4) * HL + hl) * 512;   // batch b4+4
    const float2* __restrict__ cw2 = (const float2*)cw;
    const int wrow = hl * 512;

    // pack: z = x1 + i*x2, natural layout (lane r holds z[64j + r])
    float2 v[8];
    #pragma unroll
    for (int j = 0; j < 8; ++j) {
        v[j].x = x[row1 + 64*j + lane];
        v[j].y = x[row2 + 64*j + lane];
    }

    fft512(v, lane, lane, s_re[wid], s_im[wid]);

    // lane holds Z[k], k = ds(lane) + 64*j2
    const int dsl = ((lane & 7) << 3) | (lane >> 3);
    #pragma unroll
    for (int j2 = 0; j2 < 8; ++j2) {
        const int k  = dsl + 64*j2;
        const int nk = (512 - k) & 511;
        const float2 wk  = cw2[wrow + k];
        const float2 wnk = cw2[wrow + nk];
        const float2 wp  = make_float2(0.5f*(wk.x + wnk.x), 0.5f*(wk.y - wnk.y)); // (W[k]+conj(W[N-k]))/2
        const float2 g   = cmul(wp, v[j2]);
        v[j2] = make_float2(g.x, -g.y);      // conj(G) for inverse-via-forward
    }

    fft512(v, dsl, lane, s_re[wid], s_im[wid]);

    // Y = fft(conj(G)); out1 = Re(Y)/512, out2 = -Im(Y)/512, at k = ds(lane)+64*j2
    const float inv = 1.0f / 512.0f;
    #pragma unroll
    for (int j2 = 0; j2 < 8; ++j2) {
        const int k = dsl + 64*j2;
        out[row1 + k] =  v[j2].x * inv;
        out[row2 + k] = -v[j2].y * inv;
    }
}

extern "C" void kernel_launch(void* const* d_in, const int* in_sizes, int n_in,
                              void* d_out, int out_size, void* d_ws, size_t ws_size,
                              hipStream_t stream) {
    const float* x  = (const float*)d_in[0];   // (B,H,L,D) fp32
    // d_in[1] = mask, unused
    const float* cw = (const float*)d_in[2];   // (H,L,D,2) fp32
    float* out = (float*)d_out;

    // grid: one block per (h,l); 4 waves = batch-pairs (b, b+4), b in [0,4)
    sgn_fft_r8<<<dim3(HL), dim3(256), 0, stream>>>(x, cw, out);
}

// Round 3
// 485.385 us; speedup vs baseline: 2.1850x; 1.0223x over previous
//
#include <hip/hip_runtime.h>
#include <math.h>

// (B,H,L,D) = (8,8,2048,512).  rows = B*H*L = 131072, FFT length 512.
// Identity:  Re(ifft(W . fft(x))) == ifft(Wp . fft(x)),  Wp[k] = (W[k]+conj(W[(N-k)%N]))/2
// Wp Hermitian => real result for real x; map is C-linear, so two real rows sharing a
// weight row pack as z = x1 + i*x2:  ifft(Wp.fft(z)) = out1 + i*out2 exactly.
// Inverse via forward FFT:  ifft(G) = conj(fft(conj(G)))/N  (the /N is folded into Wp).

#define HL 16384      // H*L
#define NWAVE 4       // packed pairs (waves) per block; each wave has private scratch

__device__ __forceinline__ float2 cadd(float2 a, float2 b){ return make_float2(a.x+b.x, a.y+b.y); }
__device__ __forceinline__ float2 csub(float2 a, float2 b){ return make_float2(a.x-b.x, a.y-b.y); }
__device__ __forceinline__ float2 cmul(float2 a, float2 b){ return make_float2(a.x*b.x - a.y*b.y, a.x*b.y + a.y*b.x); }

// exp(-2*pi*i*f), f in revolutions. v_sin_f32/v_cos_f32 take revolutions -> 1 inst each.
__device__ __forceinline__ float2 twiddle(float f) {
    return make_float2(__builtin_amdgcn_cosf(f), -__builtin_amdgcn_sinf(f));
}

// Wave-level LDS ordering: scratch is private to the wave, so no block barrier needed.
__device__ __forceinline__ void wave_lds_fence() {
    asm volatile("s_waitcnt lgkmcnt(0)" ::: "memory");
    __builtin_amdgcn_wave_barrier();
}

// 8-point DFT, natural order, forward sign.
__device__ __forceinline__ void fft8(float2 x[8]) {
    const float c = 0.70710678118654752f;
    float2 u0 = cadd(x[0], x[4]);
    float2 u1 = cadd(x[1], x[5]);
    float2 u2 = cadd(x[2], x[6]);
    float2 u3 = cadd(x[3], x[7]);
    float2 v0 = csub(x[0], x[4]);
    float2 t1 = csub(x[1], x[5]);
    float2 t2 = csub(x[2], x[6]);
    float2 t3 = csub(x[3], x[7]);
    float2 v1 = make_float2(c*(t1.x + t1.y), c*(t1.y - t1.x));   // * W8^1
    float2 v2 = make_float2(t2.y, -t2.x);                        // * W8^2
    float2 v3 = make_float2(c*(t3.y - t3.x), -c*(t3.x + t3.y));  // * W8^3
    float2 p0 = cadd(u0, u2), p1 = cadd(u1, u3);
    float2 q0 = csub(u0, u2), q1t = csub(u1, u3);
    float2 q1 = make_float2(q1t.y, -q1t.x);
    x[0] = cadd(p0, p1);
    x[4] = csub(p0, p1);
    x[2] = cadd(q0, q1);
    x[6] = csub(q0, q1);
    float2 r0 = cadd(v0, v2), r1 = cadd(v1, v3);
    float2 s0 = csub(v0, v2), s1t = csub(v1, v3);
    float2 s1 = make_float2(s1t.y, -s1t.x);
    x[1] = cadd(r0, r1);
    x[5] = csub(r0, r1);
    x[3] = cadd(s0, s1);
    x[7] = csub(s0, s1);
}

// 512-pt forward FFT, one wave, 8 complex per lane, AoS float2 scratch (8*72 per wave).
// Input: lane with role r holds z[64*j + r] in v[j].
// Output: lane holds Z[ds(lane) + 64*j] in v[j], ds(r) = ((r&7)<<3)|(r>>3).
// All LDS patterns spread exactly 4 lanes/bank (b64) = bandwidth minimum.
__device__ __forceinline__ void fft512(float2 v[8], int role, int lane, float2* sc)
{
    // ---- stage 1: radix-8 over stride 64, twiddle W512^{role*k1} ----
    fft8(v);
    {
        const float2 w1 = twiddle((float)role * (1.0f/512.0f));
        float2 w = w1;
        v[1] = cmul(v[1], w);
        #pragma unroll
        for (int k = 2; k < 8; ++k) { w = cmul(w, w1); v[k] = cmul(v[k], w); }
    }
    wave_lds_fence();                // WAR: prior reads of scratch drained
    #pragma unroll
    for (int k1 = 0; k1 < 8; ++k1) sc[k1*72 + role] = v[k1];
    wave_lds_fence();
    // ---- stage 2: 8 independent 64-pt FFTs; radix-8 over stride 8 ----
    const int k1 = lane >> 3, m2 = lane & 7;
    float2 u[8];
    #pragma unroll
    for (int m1 = 0; m1 < 8; ++m1) u[m1] = sc[k1*72 + 8*m1 + m2];
    fft8(u);
    {
        const float2 w1 = twiddle((float)m2 * (1.0f/64.0f));
        float2 w = w1;
        u[1] = cmul(u[1], w);
        #pragma unroll
        for (int j = 2; j < 8; ++j) { w = cmul(w, w1); u[j] = cmul(u[j], w); }
    }
    wave_lds_fence();                // WAR: stage-2 reads done before overwrite
    #pragma unroll
    for (int j1 = 0; j1 < 8; ++j1) sc[k1*72 + 9*j1 + m2] = u[j1];
    wave_lds_fence();
    // ---- stage 3: radix-8 over stride 1, no twiddle ----
    const int j1 = lane & 7;
    #pragma unroll
    for (int m = 0; m < 8; ++m) v[m] = sc[k1*72 + 9*j1 + m];
    fft8(v);                         // v[j2] = X[k1 + 8*j1 + 64*j2]
}

__global__ __launch_bounds__(256) void sgn_fft_r8(
    const float* __restrict__ x,
    const float* __restrict__ cw,    // (H,L,512,2)
    float* __restrict__ out)
{
    __shared__ float2 sc[NWAVE][8*72];

    const int tid  = threadIdx.x;
    const int wid  = tid >> 6;       // wave id = batch-pair index b4 in [0,4)
    const int lane = tid & 63;
    const int hl   = blockIdx.x;     // weight row, shared by all 4 waves (L1 reuse)

    const int row1 = (wid       * HL + hl) * 512;   // batch b4
    const int row2 = ((wid + 4) * HL + hl) * 512;   // batch b4+4
    const float2* __restrict__ cw2 = (const float2*)cw;
    const int wrow = hl * 512;

    // pack: z = x1 + i*x2, lane r holds z[64j + r]
    float2 v[8];
    #pragma unroll
    for (int j = 0; j < 8; ++j) {
        v[j].x = x[row1 + 64*j + lane];
        v[j].y = x[row2 + 64*j + lane];
    }

    fft512(v, lane, lane, sc[wid]);

    // gate: G = Wp * Z (Wp pre-scaled by 1/512), then conj for inverse-via-forward
    const int dsl = ((lane & 7) << 3) | (lane >> 3);
    const float hs = 0.5f / 512.0f;
    #pragma unroll
    for (int j2 = 0; j2 < 8; ++j2) {
        const int k  = dsl + 64*j2;
        const int nk = (512 - k) & 511;
        const float2 wk  = cw2[wrow + k];
        const float2 wnk = cw2[wrow + nk];
        const float2 wp  = make_float2(hs*(wk.x + wnk.x), hs*(wk.y - wnk.y));
        const float2 g   = cmul(wp, v[j2]);
        v[j2] = make_float2(g.x, -g.y);
    }

    fft512(v, dsl, lane, sc[wid]);

    // Y = fft(conj(G)); out1 = Re(Y), out2 = -Im(Y) at k = ds(lane)+64*j2
    #pragma unroll
    for (int j2 = 0; j2 < 8; ++j2) {
        const int k = dsl + 64*j2;
        out[row1 + k] =  v[j2].x;
        out[row2 + k] = -v[j2].y;
    }
}

extern "C" void kernel_launch(void* const* d_in, const int* in_sizes, int n_in,
                              void* d_out, int out_size, void* d_ws, size_t ws_size,
                              hipStream_t stream) {
    const float* x  = (const float*)d_in[0];   // (B,H,L,D) fp32
    // d_in[1] = mask, unused
    const float* cw = (const float*)d_in[2];   // (H,L,D,2) fp32
    float* out = (float*)d_out;

    sgn_fft_r8<<<dim3(HL), dim3(256), 0, stream>>>(x, cw, out);
}